// Round 1
// baseline (206.292 us; speedup 1.0000x reference)
//
#include <hip/hip_runtime.h>
#include <math.h>

// Tropical (max-plus) depthwise 3x3 conv, stride=1, pad=1, dil=1.
// x: (B=8, C=64, H=224, W=224) fp32, kernel: (64,1,3,3) fp32, out same shape as x.
// One thread -> one aligned float4 of one output row. Memory-bound design:
// coalesced 16B loads/stores; vertical 3x row reuse absorbed by L1/L2.

#define H_DIM 224
#define W_DIM 224
#define W4 56            // W/4
#define C_DIM 64

__global__ __launch_bounds__(256) void tropical_conv_kernel(
    const float* __restrict__ x,
    const float* __restrict__ kern,
    float* __restrict__ out,
    int total)   // total float4 outputs = B*C*H*W4
{
    int idx = blockIdx.x * blockDim.x + threadIdx.x;
    if (idx >= total) return;

    const float NEG = -INFINITY;

    int j4 = idx % W4;          // which float4 within the row
    int t  = idx / W4;
    int i  = t % H_DIM;         // output row
    int bc = t / H_DIM;         // fused batch*channel plane index
    int c  = bc & (C_DIM - 1);

    const float* kc    = kern + c * 9;          // 3x3 taps for this channel
    const float* plane = x + (size_t)bc * (H_DIM * W_DIM);
    int j0 = j4 * 4;

    float4 acc = make_float4(NEG, NEG, NEG, NEG);

    #pragma unroll
    for (int ki = 0; ki < 3; ++ki) {
        int r = i + ki - 1;
        if (r < 0 || r >= H_DIM) continue;
        const float* row = plane + r * W_DIM;

        float4 a    = *(const float4*)(row + j0);
        float left  = (j4 > 0)        ? row[j0 - 1] : NEG;
        float right = (j4 < W4 - 1)   ? row[j0 + 4] : NEG;

        float k0 = kc[ki * 3 + 0];
        float k1 = kc[ki * 3 + 1];
        float k2 = kc[ki * 3 + 2];

        // out[j] = max(x[j-1]+k0, x[j]+k1, x[j+1]+k2)
        acc.x = fmaxf(acc.x, fmaxf(fmaxf(left + k0, a.x + k1), a.y  + k2));
        acc.y = fmaxf(acc.y, fmaxf(fmaxf(a.x  + k0, a.y + k1), a.z  + k2));
        acc.z = fmaxf(acc.z, fmaxf(fmaxf(a.y  + k0, a.z + k1), a.w  + k2));
        acc.w = fmaxf(acc.w, fmaxf(fmaxf(a.z  + k0, a.w + k1), right + k2));
    }

    float4* op = (float4*)(out + (size_t)bc * (H_DIM * W_DIM) + (size_t)i * W_DIM + j0);
    *op = acc;
}

extern "C" void kernel_launch(void* const* d_in, const int* in_sizes, int n_in,
                              void* d_out, int out_size, void* d_ws, size_t ws_size,
                              hipStream_t stream) {
    const float* x    = (const float*)d_in[0];
    const float* kern = (const float*)d_in[1];
    float* out        = (float*)d_out;

    // B*C*H*W4 = 8*64*224*56
    const int total = 8 * C_DIM * H_DIM * W4;
    const int block = 256;
    const int grid  = (total + block - 1) / block;
    tropical_conv_kernel<<<grid, block, 0, stream>>>(x, kern, out, total);
}

// Round 2
// 183.376 us; speedup vs baseline: 1.1250x; 1.1250x over previous
//
#include <hip/hip_runtime.h>
#include <math.h>

// Tropical (max-plus) depthwise 3x3 conv, stride=1, pad=1, dil=1.
// x: (B=8, C=64, H=224, W=224) fp32; kernel: (64,1,3,3) fp32; out = x shape.
// R1 design: one thread -> 4 output rows x 1 float4 (16 outputs).
//   - 6 independent row loads issued up front (latency hiding via MLP),
//   - register-level vertical reuse: 1.5 float4 loads per output row vs 3,
//   - coalesced: consecutive lanes -> consecutive float4 in same row.

#define H_DIM 224
#define W_DIM 224
#define W4 56            // W/4
#define G4 56            // H/4 row-groups (4 output rows per group)
#define C_DIM 64

__global__ __launch_bounds__(256) void tropical_conv_kernel(
    const float* __restrict__ x,
    const float* __restrict__ kern,
    float* __restrict__ out,
    int total)   // total threads = B*C*G4*W4
{
    int idx = blockIdx.x * blockDim.x + threadIdx.x;
    if (idx >= total) return;

    const float NEG = -INFINITY;

    int j4 = idx % W4;          // float4 index within the row
    int t  = idx / W4;
    int g  = t % G4;            // row-group (4 output rows)
    int bc = t / G4;            // fused batch*channel plane
    int c  = bc & (C_DIM - 1);

    const float* kc = kern + c * 9;
    float k00 = kc[0], k01 = kc[1], k02 = kc[2];
    float k10 = kc[3], k11 = kc[4], k12 = kc[5];
    float k20 = kc[6], k21 = kc[7], k22 = kc[8];

    const float* plane = x + (size_t)bc * (H_DIM * W_DIM);
    int j0 = j4 * 4;
    int i0 = g * 4;

    // Load 6 input rows (i0-1 .. i0+4) with horizontal halos.
    float4 rv[6];
    float  lf[6], rg[6];
    #pragma unroll
    for (int rr = 0; rr < 6; ++rr) {
        int r = i0 - 1 + rr;
        if (r >= 0 && r < H_DIM) {
            const float* row = plane + r * W_DIM;
            rv[rr] = *(const float4*)(row + j0);
            lf[rr] = (j4 > 0)      ? row[j0 - 1] : NEG;
            rg[rr] = (j4 < W4 - 1) ? row[j0 + 4] : NEG;
        } else {
            rv[rr] = make_float4(NEG, NEG, NEG, NEG);
            lf[rr] = NEG;
            rg[rr] = NEG;
        }
    }

    float* oplane = out + (size_t)bc * (H_DIM * W_DIM);

    #pragma unroll
    for (int o = 0; o < 4; ++o) {
        float4 acc = make_float4(NEG, NEG, NEG, NEG);
        #pragma unroll
        for (int ki = 0; ki < 3; ++ki) {
            int rr = o + ki;
            float t0 = (ki == 0) ? k00 : (ki == 1) ? k10 : k20;
            float t1 = (ki == 0) ? k01 : (ki == 1) ? k11 : k21;
            float t2 = (ki == 0) ? k02 : (ki == 1) ? k12 : k22;
            float4 a = rv[rr];
            acc.x = fmaxf(acc.x, fmaxf(fmaxf(lf[rr] + t0, a.x + t1), a.y   + t2));
            acc.y = fmaxf(acc.y, fmaxf(fmaxf(a.x   + t0, a.y + t1), a.z   + t2));
            acc.z = fmaxf(acc.z, fmaxf(fmaxf(a.y   + t0, a.z + t1), a.w   + t2));
            acc.w = fmaxf(acc.w, fmaxf(fmaxf(a.z   + t0, a.w + t1), rg[rr] + t2));
        }
        *(float4*)(oplane + (size_t)(i0 + o) * W_DIM + j0) = acc;
    }
}

extern "C" void kernel_launch(void* const* d_in, const int* in_sizes, int n_in,
                              void* d_out, int out_size, void* d_ws, size_t ws_size,
                              hipStream_t stream) {
    const float* x    = (const float*)d_in[0];
    const float* kern = (const float*)d_in[1];
    float* out        = (float*)d_out;

    const int total = 8 * C_DIM * G4 * W4;   // 1,605,632 threads
    const int block = 256;
    const int grid  = (total + block - 1) / block;
    tropical_conv_kernel<<<grid, block, 0, stream>>>(x, kern, out, total);
}